// Round 8
// baseline (253.130 us; speedup 1.0000x reference)
//
#include <hip/hip_runtime.h>
#include <stdint.h>

typedef unsigned int u32;
typedef __attribute__((ext_vector_type(8))) __bf16 bf16x8;
typedef __attribute__((ext_vector_type(4))) __bf16 bf16x4;
typedef __attribute__((ext_vector_type(8))) short s16x8;
typedef __attribute__((ext_vector_type(4))) short s16x4;
typedef __attribute__((ext_vector_type(4))) float f32x4;

// ---------- helpers ----------

__device__ __forceinline__ short f2bf(float f) {
    __bf16 h = (__bf16)f;               // native v_cvt, RNE
    return __builtin_bit_cast(short, h);
}

__device__ __forceinline__ bf16x8 asbf(s16x8 v) {
    return __builtin_bit_cast(bf16x8, v);
}

__device__ __forceinline__ f32x4 mfma32(s16x8 a, s16x8 b, f32x4 c) {
    return __builtin_amdgcn_mfma_f32_16x16x32_bf16(asbf(a), asbf(b), c, 0, 0, 0);
}

// K=16 bf16 MFMA: lane holds k = quad*4+j for A and B — matches S^T C-layout.
// NOTE: must be fenced from the HOST pass (__has_builtin alone is not a guard —
// that's what broke R7). Device builtin spelling is ...16x16x16bf16_1k (v4i16).
__device__ __forceinline__ f32x4 mfma16(s16x4 a, s16x4 b, f32x4 c) {
#if defined(__AMDGCN__)
#if __has_builtin(__builtin_amdgcn_mfma_f32_16x16x16bf16_1k)
    return __builtin_amdgcn_mfma_f32_16x16x16bf16_1k(a, b, c, 0, 0, 0);
#else
    f32x4 d;
    asm volatile("v_mfma_f32_16x16x16_bf16 %0, %1, %2, %3"
                 : "=v"(d) : "v"(a), "v"(b), "v"(c));
    return d;
#endif
#else
    (void)a; (void)b;
    return c;   // host pass: never executed
#endif
}

// async global->LDS, 16B per lane (proj staging only)
__device__ __forceinline__ void gl_lds16(const void* g, void* l) {
    __builtin_amdgcn_global_load_lds((__attribute__((address_space(1))) u32*)g,
                                     (__attribute__((address_space(3))) u32*)l,
                                     16, 0, 0);
}

// Packed tile format: 128x64 tile = 16 chunks of 512 shorts; ch = c*8+ig;
// within chunk offset = lane*8+j holds [row=ig*16+(lane&15)][col=c*32+(lane>>4)*8+j].
// 64x64 tile = 8 chunks, ch = c*4+ig, same rule.

// ---------- pack kernel ----------

__global__ __launch_bounds__(256) void pack_tiles(
    const float* __restrict__ x,  short* __restrict__ xP,
    const float* __restrict__ y,  short* __restrict__ yP,
    const float* __restrict__ wqx, short* __restrict__ wqxP,
    const float* __restrict__ wqy, short* __restrict__ wqyP,
    const float* __restrict__ wpx, short* __restrict__ wpxP,
    const float* __restrict__ wpy, short* __restrict__ wpyP)
{
    const int tid  = threadIdx.x;
    const int w    = tid >> 6, lane = tid & 63;
    const int lam  = lane & 15, quad = lane >> 4;

    int t = blockIdx.x;
    const float* src; short* dst;
    if (t < 384)                 { src = x;   dst = xP; }
    else if ((t -= 384) < 384)   { src = y;   dst = yP; }
    else if ((t -= 384) < 216)   { src = wqx; dst = wqxP; }
    else if ((t -= 216) < 216)   { src = wqy; dst = wqyP; }
    else if ((t -= 216) < 72)    { src = wpx; dst = wpxP; }
    else                         { t -= 72;  src = wpy; dst = wpyP; }

    const int kb = t % 12, rb = t / 12;
    const int m0 = rb * 128, k0 = kb * 64;
    short* dtile = dst + (size_t)t * 8192;

    #pragma unroll
    for (int u = 0; u < 2; u++) {
        const int ig = w * 2 + u;
        #pragma unroll
        for (int c = 0; c < 2; c++) {
            const float* sp = src + (size_t)(m0 + ig * 16 + lam) * 768 + k0 + c * 32 + quad * 8;
            f32x4 a = *(const f32x4*)sp;
            f32x4 b = *(const f32x4*)(sp + 4);
            s16x8 o;
            o[0] = f2bf(a.x); o[1] = f2bf(a.y); o[2] = f2bf(a.z); o[3] = f2bf(a.w);
            o[4] = f2bf(b.x); o[5] = f2bf(b.y); o[6] = f2bf(b.z); o[7] = f2bf(b.w);
            *(s16x8*)(dtile + (c * 8 + ig) * 512 + lane * 8) = o;
        }
    }
}

// ---------- QKV GEMM v5: barrier-free direct packed register loads ----------

__global__ __launch_bounds__(256, 2) void qkv_gemm(
    const short* __restrict__ AxP, const short* __restrict__ AyP,
    const short* __restrict__ WxP, const short* __restrict__ WyP,
    const float* __restrict__ biasx, const float* __restrict__ biasy,
    const float* __restrict__ gqx, const float* __restrict__ bqx,
    const float* __restrict__ gkx, const float* __restrict__ bkx,
    const float* __restrict__ gqy, const float* __restrict__ bqy,
    const float* __restrict__ gky, const float* __restrict__ bky,
    short* __restrict__ Q, short* __restrict__ KP, short* __restrict__ VP)
{
    __shared__ __align__(16) short lE[4][5120];   // per-wave epilogue transpose only
    const int tid  = threadIdx.x;
    const int w    = tid >> 6, lane = tid & 63;
    const int lam  = lane & 15, quad = lane >> 4;
    const int strm = blockIdx.z;
    const int mblk = blockIdx.x;          // linear%8 == mblk%8 -> XCD stripe over m
    const int nblk = blockIdx.y;
    const short* AP   = strm ? AyP : AxP;
    const short* WP   = strm ? WyP : WxP;
    const float* bias = strm ? biasy : biasx;
    const int m0 = mblk * 128;
    const int n0 = nblk * 128;
    const int wm = w >> 1, wn = w & 1;

    const short* Ap = AP + (size_t)mblk * 12 * 8192 + lane * 8;
    const short* Wp = WP + (size_t)nblk * 12 * 8192 + lane * 8;

    const f32x4 fzero = {0.f, 0.f, 0.f, 0.f};
    f32x4 acc[4][4];
    #pragma unroll
    for (int i = 0; i < 4; i++)
        #pragma unroll
        for (int t = 0; t < 4; t++) acc[i][t] = fzero;

    #define QOFF(kc_, sel_, i_) (((kc_) >> 1) * 8192 + (((kc_) & 1) * 8 + (sel_) * 4 + (i_)) * 512)

    s16x8 fa[2][4], fb[2][4];
    #pragma unroll
    for (int i = 0; i < 4; i++) fa[0][i] = *(const s16x8*)(Ap + QOFF(0, wm, i));
    #pragma unroll
    for (int t = 0; t < 4; t++) fb[0][t] = *(const s16x8*)(Wp + QOFF(0, wn, t));

    #pragma unroll
    for (int kc = 0; kc < 24; ++kc) {
        const int cur = kc & 1, nxt = cur ^ 1;
        if (kc + 1 < 24) {
            #pragma unroll
            for (int i = 0; i < 4; i++) fa[nxt][i] = *(const s16x8*)(Ap + QOFF(kc + 1, wm, i));
            #pragma unroll
            for (int t = 0; t < 4; t++) fb[nxt][t] = *(const s16x8*)(Wp + QOFF(kc + 1, wn, t));
        }
        #pragma unroll
        for (int i = 0; i < 4; i++)
            #pragma unroll
            for (int t = 0; t < 4; t++)
                acc[i][t] = mfma32(fa[cur][i], fb[cur][t], acc[i][t]);
    }
    #undef QOFF

    // ---- epilogue ----
    const int nb     = n0 + wn * 64;
    const int region = nb / 768;               // 0=q, 1=k, 2=v
    const int head   = (nb % 768) / 64;
    const int mg0    = m0 + wm * 64;
    const int b_     = mg0 >> 10;
    const int sg0    = (mg0 & 1023) + strm * 1024;
    short* myE = lE[w];

    float bv[4];
    #pragma unroll
    for (int t = 0; t < 4; t++) bv[t] = bias[nb + t * 16 + lam];
    float gv[4], bb[4];
    if (region < 2) {
        const float* gp = (region == 0) ? (strm ? gqy : gqx) : (strm ? gky : gkx);
        const float* bp = (region == 0) ? (strm ? bqy : bqx) : (strm ? bky : bkx);
        const float qs  = (region == 0) ? 0.18033688011112042f : 1.0f;  // 0.125*log2(e)
        #pragma unroll
        for (int t = 0; t < 4; t++) { gv[t] = gp[t * 16 + lam] * qs; bb[t] = bp[t * 16 + lam] * qs; }
    }

    #pragma unroll
    for (int i = 0; i < 4; i++) {
        #pragma unroll
        for (int reg = 0; reg < 4; reg++) {
            const int lr = i * 16 + quad * 4 + reg;    // local row 0..63
            float v0 = acc[i][0][reg] + bv[0];
            float v1 = acc[i][1][reg] + bv[1];
            float v2 = acc[i][2][reg] + bv[2];
            float v3 = acc[i][3][reg] + bv[3];
            if (region < 2) {
                float s = v0 + v1 + v2 + v3;
                s += __shfl_xor(s, 1); s += __shfl_xor(s, 2);
                s += __shfl_xor(s, 4); s += __shfl_xor(s, 8);
                const float mean = s * (1.f / 64.f);
                const float c0 = v0 - mean, c1 = v1 - mean, c2 = v2 - mean, c3 = v3 - mean;
                float q2 = c0 * c0 + c1 * c1 + c2 * c2 + c3 * c3;
                q2 += __shfl_xor(q2, 1); q2 += __shfl_xor(q2, 2);
                q2 += __shfl_xor(q2, 4); q2 += __shfl_xor(q2, 8);
                const float rs = rsqrtf(q2 * (1.f / 64.f) + 1e-5f);
                v0 = c0 * rs * gv[0] + bb[0];
                v1 = c1 * rs * gv[1] + bb[1];
                v2 = c2 * rs * gv[2] + bb[2];
                v3 = c3 * rs * gv[3] + bb[3];
                myE[lr * 80 + 0 * 16 + lam] = f2bf(v0);   // row-major [s][d]
                myE[lr * 80 + 1 * 16 + lam] = f2bf(v1);
                myE[lr * 80 + 2 * 16 + lam] = f2bf(v2);
                myE[lr * 80 + 3 * 16 + lam] = f2bf(v3);
            } else {
                myE[(0 * 16 + lam) * 80 + lr] = f2bf(v0); // transposed [d][s]
                myE[(1 * 16 + lam) * 80 + lr] = f2bf(v1);
                myE[(2 * 16 + lam) * 80 + lr] = f2bf(v2);
                myE[(3 * 16 + lam) * 80 + lr] = f2bf(v3);
            }
        }
    }

    if (region == 0) {
        const int l8 = lane >> 3, c8 = (lane & 7) * 8;
        short* dstp = Q + ((size_t)(b_ * 12 + head) * 2048 + sg0) * 64;
        #pragma unroll
        for (int j = 0; j < 8; j++) {
            const int rr = j * 8 + l8;
            *(s16x8*)(dstp + (size_t)rr * 64 + c8) = *(const s16x8*)(myE + rr * 80 + c8);
        }
    } else {
        short* dstp = (region == 1 ? KP : VP) +
                      ((size_t)(b_ * 12 + head) * 32 + (sg0 >> 6)) * 4096;
        #pragma unroll
        for (int c = 0; c < 2; c++)
            #pragma unroll
            for (int ig = 0; ig < 4; ig++) {
                s16x8 vv = *(const s16x8*)(myE + (ig * 16 + lam) * 80 + c * 32 + quad * 8);
                *(s16x8*)(dstp + (c * 4 + ig) * 512 + lane * 8) = vv;
            }
    }
}

// ---------- flash attention v4: S^T + K=16 PV, P never leaves the lane ----------

__global__ __launch_bounds__(256, 2) void attn(
    const short* __restrict__ Q, const short* __restrict__ KP,
    const short* __restrict__ VP, short* __restrict__ OP)
{
    __shared__ __align__(16) short lO[4][2560];   // epilogue transpose only
    const int tid  = threadIdx.x;
    const int w    = tid >> 6, lane = tid & 63;
    const int lam  = lane & 15, quad = lane >> 4;
    const int bh   = blockIdx.x;
    const int q0   = blockIdx.y * 128 + w * 32;
    const short* Qb  = Q  + (size_t)bh * 2048 * 64;
    const short* KPb = KP + (size_t)bh * 32 * 4096;
    const short* VPb = VP + (size_t)bh * 32 * 4096;

    s16x8 aq[2][2];
    #pragma unroll
    for (int qf = 0; qf < 2; qf++)
        #pragma unroll
        for (int c = 0; c < 2; c++)
            aq[qf][c] = *(const s16x8*)(Qb + (size_t)(q0 + qf * 16 + lam) * 64 + c * 32 + quad * 8);

    const f32x4 fzero = {0.f, 0.f, 0.f, 0.f};
    const f32x4 minit = {-30.f, -30.f, -30.f, -30.f};
    f32x4 o[2][4];
    float lsum[2] = {0.f, 0.f};
    #pragma unroll
    for (int qf = 0; qf < 2; qf++)
        #pragma unroll
        for (int t = 0; t < 4; t++) o[qf][t] = fzero;

    // per-lane V b64 sub-offsets (t-parity selects the 512B half)
    const int vsub0 = ((0 * 2 + (quad >> 1)) * 16 + lam) * 8 + (quad & 1) * 4;  // t even
    const int vsub1 = ((1 * 2 + (quad >> 1)) * 16 + lam) * 8 + (quad & 1) * 4;  // t odd

    for (int it = 0; it < 32; ++it) {
        const short* kt = KPb + (size_t)it * 4096;
        const short* vt = VPb + (size_t)it * 4096;

        // K A-frags: 8 x 1KB-contiguous b128 loads (shared across both q-tiles)
        s16x8 kf[4][2];
        #pragma unroll
        for (int t = 0; t < 4; t++) {
            kf[t][0] = *(const s16x8*)(kt + (0 * 4 + t) * 512 + lane * 8);
            kf[t][1] = *(const s16x8*)(kt + (1 * 4 + t) * 512 + lane * 8);
        }
        // V B-frags for K=16 MFMA: 16 x 512B-contiguous b64 loads
        // vb[dt][t] = V[kk=t*16+quad*4+j][d=dt*16+lam]
        s16x4 vb[4][4];
        #pragma unroll
        for (int dt = 0; dt < 4; dt++)
            #pragma unroll
            for (int t = 0; t < 4; t++)
                vb[dt][t] = *(const s16x4*)(vt + ((t >> 1) * 4 + dt) * 512 +
                                            ((t & 1) ? vsub1 : vsub0));

        #pragma unroll
        for (int qf = 0; qf < 2; qf++) {
            // S^T scores: col=q=lane&15, row=kk=quad*4+reg; C init = -30
            f32x4 sc[4];
            #pragma unroll
            for (int t = 0; t < 4; t++) sc[t] = minit;
            #pragma unroll
            for (int t = 0; t < 4; t++) {
                sc[t] = mfma32(kf[t][0], aq[qf][0], sc[t]);
                sc[t] = mfma32(kf[t][1], aq[qf][1], sc[t]);
            }
            // p = exp2(sc) in-register; build K=16 A-frags directly
            s16x4 pf[4];
            float ls = 0.f;
            #pragma unroll
            for (int t = 0; t < 4; t++)
                #pragma unroll
                for (int r = 0; r < 4; r++) {
                    const float p = __builtin_amdgcn_exp2f(sc[t][r]);
                    ls += p;
                    pf[t][r] = f2bf(p);
                }
            lsum[qf] += ls;
            // O += P @ V via 16x16x16 MFMA
            #pragma unroll
            for (int dt = 0; dt < 4; dt++)
                #pragma unroll
                for (int t = 0; t < 4; t++)
                    o[qf][dt] = mfma16(pf[t], vb[dt][t], o[qf][dt]);
        }
    }

    // ---- epilogue: reduce l across quads, normalize, transpose, packed O ----
    short* myO = lO[w];
    #pragma unroll
    for (int qf = 0; qf < 2; qf++) {
        float l = lsum[qf];
        l += __shfl_xor(l, 16);
        l += __shfl_xor(l, 32);          // every lane: total l for q = lam
        #pragma unroll
        for (int r = 0; r < 4; r++) {
            const float inv = 1.0f / __shfl(l, quad * 4 + r, 16);
            const int row = qf * 16 + quad * 4 + r;
            #pragma unroll
            for (int t = 0; t < 4; t++)
                myO[row * 80 + t * 16 + lam] = f2bf(o[qf][t][r] * inv);
        }
    }

    const int b_ = bh / 12, h_ = bh % 12;
    const int strm = q0 >> 10;
    const int s    = q0 & 1023;
    const int sb   = s >> 6;
    short* dstp = OP + (((size_t)((strm * 4 + b_) * 16 + sb)) * 12 + h_) * 4096;
    const int igb = (s & 63) >> 4;
    #pragma unroll
    for (int u = 0; u < 2; u++) {
        const int ig = igb + u;
        #pragma unroll
        for (int c = 0; c < 2; c++) {
            s16x8 vv = *(const s16x8*)(myO + (u * 16 + lam) * 80 + c * 32 + quad * 8);
            *(s16x8*)(dstp + (c * 4 + ig) * 512 + lane * 8) = vv;
        }
    }
}

// ---------- proj GEMM (unchanged R5 structure) ----------

__device__ __forceinline__ void stage_proj(
    const short* __restrict__ Ot, const short* __restrict__ Wt,
    short* __restrict__ dA, short* __restrict__ dB, int w, int lane)
{
    #pragma unroll
    for (int u = 0; u < 2; u++) {
        const int ch = w * 2 + u;
        gl_lds16(Ot + ch * 512 + lane * 8, dA + ch * 512);
    }
    #pragma unroll
    for (int c = 0; c < 2; c++)
        #pragma unroll
        for (int h = 0; h < 2; h++) {
            const int ch = c * 8 + w + h * 4;
            gl_lds16(Wt + ch * 512 + lane * 8, dB + ch * 512);
        }
}

__global__ __launch_bounds__(256, 3) void proj_gemm(
    const short* __restrict__ OP,
    const short* __restrict__ WpxP, const short* __restrict__ WpyP,
    const float* __restrict__ bpx, const float* __restrict__ bpy,
    float* __restrict__ out)
{
    __shared__ __align__(16) short lA[2][4096];
    __shared__ __align__(16) short lB[2][8192];
    const int tid  = threadIdx.x;
    const int w    = tid >> 6, lane = tid & 63;
    const int lam  = lane & 15, quad = lane >> 4;
    const int strm = blockIdx.z;
    const short* WP   = strm ? WpyP : WpxP;
    const float* bias = strm ? bpy : bpx;
    const int m0 = blockIdx.x * 64;
    const int n0 = blockIdx.y * 128;
    const int wm = w >> 1, wn = w & 1;

    const int b_ = m0 >> 10, sb = (m0 & 1023) >> 6;
    const size_t tA0 = ((size_t)((strm * 4 + b_) * 16 + sb)) * 12;
    const size_t tB0 = (size_t)blockIdx.y * 12;

    const f32x4 fzero = {0.f, 0.f, 0.f, 0.f};
    f32x4 acc[2][4];
    #pragma unroll
    for (int i = 0; i < 2; i++)
        #pragma unroll
        for (int t = 0; t < 4; t++) acc[i][t] = fzero;

    stage_proj(OP + tA0 * 4096, WP + tB0 * 8192, lA[0], lB[0], w, lane);
    __syncthreads();

    int bi = 0;
    for (int kb = 0; kb < 12; ++kb) {
        if (kb + 1 < 12)
            stage_proj(OP + (tA0 + kb + 1) * 4096, WP + (tB0 + kb + 1) * 8192,
                       lA[bi ^ 1], lB[bi ^ 1], w, lane);

        const short* cA = lA[bi];
        const short* cB = lB[bi];
        s16x8 af[2][2], bfr[2][4];
        #pragma unroll
        for (int c = 0; c < 2; c++)
            #pragma unroll
            for (int i = 0; i < 2; i++)
                af[c][i] = *(const s16x8*)(cA + ((c * 4 + wm * 2 + i) * 64 + lane) * 8);
        #pragma unroll
        for (int c = 0; c < 2; c++)
            #pragma unroll
            for (int t = 0; t < 4; t++)
                bfr[c][t] = *(const s16x8*)(cB + ((c * 8 + wn * 4 + t) * 64 + lane) * 8);
        #pragma unroll
        for (int c = 0; c < 2; c++)
            #pragma unroll
            for (int i = 0; i < 2; i++)
                #pragma unroll
                for (int t = 0; t < 4; t++)
                    acc[i][t] = mfma32(af[c][i], bfr[c][t], acc[i][t]);

        __syncthreads();
        bi ^= 1;
    }

    const int nb = n0 + wn * 64;
    float bv[4];
    #pragma unroll
    for (int t = 0; t < 4; t++) bv[t] = bias[nb + t * 16 + lam];
    #pragma unroll
    for (int i = 0; i < 2; i++) {
        #pragma unroll
        for (int reg = 0; reg < 4; reg++) {
            const int mg = m0 + wm * 32 + i * 16 + quad * 4 + reg;
            float* dst = out + (size_t)strm * 3145728 + (size_t)mg * 768 + nb;
            #pragma unroll
            for (int t = 0; t < 4; t++) dst[t * 16 + lam] = acc[i][t][reg] + bv[t];
        }
    }
}

// ---------- launch ----------

#define WS_XP  0
#define WS_YP  6291456
#define WS_WQX 12582912
#define WS_WQY 16121856
#define WS_WPX 19660800
#define WS_WPY 20840448
#define WS_Q   22020096
#define WS_KP  34603008
#define WS_VP  47185920
#define WS_OP  59768832

extern "C" void kernel_launch(void* const* d_in, const int* in_sizes, int n_in,
                              void* d_out, int out_size, void* d_ws, size_t ws_size,
                              hipStream_t stream) {
    (void)in_sizes; (void)n_in; (void)out_size; (void)ws_size;
    const float* x       = (const float*)d_in[0];
    const float* y       = (const float*)d_in[1];
    const float* Wqkv_x  = (const float*)d_in[2];
    const float* bqkv_x  = (const float*)d_in[3];
    const float* Wqkv_y  = (const float*)d_in[4];
    const float* bqkv_y  = (const float*)d_in[5];
    const float* Wproj_x = (const float*)d_in[6];
    const float* bproj_x = (const float*)d_in[7];
    const float* Wproj_y = (const float*)d_in[8];
    const float* bproj_y = (const float*)d_in[9];
    const float* gq_x = (const float*)d_in[10];
    const float* bq_x = (const float*)d_in[11];
    const float* gk_x = (const float*)d_in[12];
    const float* bk_x = (const float*)d_in[13];
    const float* gq_y = (const float*)d_in[14];
    const float* bq_y = (const float*)d_in[15];
    const float* gk_y = (const float*)d_in[16];
    const float* bk_y = (const float*)d_in[17];

    char* ws = (char*)d_ws;
    short* xP   = (short*)(ws + WS_XP);
    short* yP   = (short*)(ws + WS_YP);
    short* wqxP = (short*)(ws + WS_WQX);
    short* wqyP = (short*)(ws + WS_WQY);
    short* wpxP = (short*)(ws + WS_WPX);
    short* wpyP = (short*)(ws + WS_WPY);
    short* Qb   = (short*)(ws + WS_Q);
    short* KPb  = (short*)(ws + WS_KP);
    short* VPb  = (short*)(ws + WS_VP);
    short* OPb  = (short*)(ws + WS_OP);

    pack_tiles<<<1344, 256, 0, stream>>>(x, xP, y, yP, Wqkv_x, wqxP,
                                         Wqkv_y, wqyP, Wproj_x, wpxP, Wproj_y, wpyP);

    dim3 g1(32, 18, 2);
    qkv_gemm<<<g1, 256, 0, stream>>>(xP, yP, wqxP, wqyP, bqkv_x, bqkv_y,
                                     gq_x, bq_x, gk_x, bk_x,
                                     gq_y, bq_y, gk_y, bk_y,
                                     Qb, KPb, VPb);

    dim3 g2(48, 16);
    attn<<<g2, 256, 0, stream>>>(Qb, KPb, VPb, OPb);

    dim3 g3(64, 6, 2);
    proj_gemm<<<g3, 256, 0, stream>>>(OPb, wpxP, wpyP, bproj_x, bproj_y, (float*)d_out);
}